// Round 2
// baseline (693.408 us; speedup 1.0000x reference)
//
#include <hip/hip_runtime.h>
#include <hip/hip_fp16.h>

// Deep-BSDE fused forward, round 2: wave-independent tiles, zero in-loop barriers.
//
// y[b] = y0 + sum_t [ DT*LAM*sum_d z^2 + sum_d z*dw ]  (z never feeds back into y)
// => all 409,600 (b,t) rows are independent 3-layer MLP evaluations.
//
// Each wave owns a 32-row tile: stage x -> L1 -> L2 -> L3 (in-place h repack in a
// private LDS slice), z*dw from global, 2 atomicAdd into out[]. Weights are staged
// once per block into swizzled LDS (read-only afterwards -> no barrier needed).

#define DIMX 100
#define TS   50
#define HID  110
#define KA   128          // f16 elems per LDS row (256B), XOR-swizzled
#define W1R  0
#define W2R  110
#define W3R  220
#define WROWS 320
#define NROWS (8192 * TS) // 409600
#define NTILES (NROWS / 32)   // 12800
#define NWAVES 2048           // 256 blocks * 8 waves
#define DTCO 0.02f

typedef _Float16 f16;
typedef _Float16 f16x8 __attribute__((ext_vector_type(8)));
typedef float    f32x16 __attribute__((ext_vector_type(16)));

// swizzle: permute 8-elem (16B) blocks within a 128-elem (256B) row by row&7
__device__ __forceinline__ int swz(int row, int col) {
    return row * KA + (col ^ ((row & 7) << 3));
}

__device__ __forceinline__ void run_layer(const f16* __restrict__ wlds, int wbase, int nmax,
                                          const f16* __restrict__ abuf,
                                          int ln, int hi, f32x16 acc[4])
{
    const int xr = (ln & 7) << 3;
    int brow[4], bxr[4];
#pragma unroll
    for (int nt = 0; nt < 4; ++nt) {
        int n = 32 * nt + ln;
        if (n > nmax) n = nmax;          // clamped read: finite garbage, masked later
        brow[nt] = (wbase + n) * KA;
        bxr[nt]  = ((wbase + n) & 7) << 3;
    }
#pragma unroll
    for (int ks = 0; ks < 7; ++ks) {
        const int k = ks * 16 + hi * 8;
        const f16x8 a = *(const f16x8*)(abuf + ln * KA + (k ^ xr));
#pragma unroll
        for (int nt = 0; nt < 4; ++nt) {
            const f16x8 bv = *(const f16x8*)(wlds + brow[nt] + (k ^ bxr[nt]));
            acc[nt] = __builtin_amdgcn_mfma_f32_32x32x16_f16(a, bv, acc[nt], 0, 0, 0);
        }
    }
}

__device__ __forceinline__ void store_h(f16* __restrict__ abuf, const f32x16 acc[4],
                                        int ln, int hi)
{
#pragma unroll
    for (int nt = 0; nt < 4; ++nt) {
        const int col = 32 * nt + ln;
        if (col < 112) {                          // k-pad cols 110,111 get zero
            const bool live = col < HID;
#pragma unroll
            for (int q = 0; q < 16; ++q) {
                const int row = (q & 3) + 8 * (q >> 2) + 4 * hi;
                float v = live ? (float)acc[nt][q] : 0.f;
                v = v > 0.f ? v : 0.f;            // relu
                abuf[swz(row, col)] = (f16)v;
            }
        }
    }
}

__global__ void init_out(float* __restrict__ out, const float* __restrict__ y0) {
    const int i = blockIdx.x * blockDim.x + threadIdx.x;
    if (i < 8192) out[i] = y0[0];
}

__launch_bounds__(512, 2)
__global__ void bsde_kernel(const float* __restrict__ dw, const float* __restrict__ x,
                            const float* __restrict__ W1, const float* __restrict__ W2,
                            const float* __restrict__ W3, float* __restrict__ out)
{
    __shared__ __align__(16) f16 lds[(WROWS + 8 * 32) * KA];   // 147,456 B

    const int tid  = threadIdx.x;
    const int lane = tid & 63;
    const int w    = tid >> 6;
    const int ln   = lane & 31;
    const int hi   = lane >> 5;
    f16* __restrict__ mybuf = lds + (WROWS + w * 32) * KA;

    // ---- prepass: zero everything, then stage weights (swizzled, transposed) ----
    {
        int4* p = (int4*)lds;
        const int n16 = (WROWS + 8 * 32) * KA / 8;
        for (int i = tid; i < n16; i += 512) p[i] = int4{0, 0, 0, 0};
    }
    __syncthreads();
    for (int e = tid; e < 101 * HID; e += 512) {
        const int k = e / HID, n = e - k * HID;
        lds[swz(W1R + n, k)] = (f16)W1[e];
    }
    for (int e = tid; e < HID * HID; e += 512) {
        const int k = e / HID, n = e - k * HID;
        lds[swz(W2R + n, k)] = (f16)W2[e];
    }
    for (int e = tid; e < HID * DIMX; e += 512) {
        const int k = e / DIMX, n = e - k * DIMX;
        lds[swz(W3R + n, k)] = (f16)W3[e];
    }
    __syncthreads();
    // ---- no barriers from here on: each wave is fully independent ----

    const int wid = blockIdx.x * 8 + w;
    const int xr  = (ln & 7) << 3;

    for (int tile = wid; tile < NTILES; tile += NWAVES) {
        const int R0 = tile * 32;

        // ---------- stage x: 32 rows x 100 d into private slice ----------
        {
            const int r = R0 + ln;                 // this lane's row (both hi halves)
            const int b = (int)((unsigned)r / 50u);
            const int t = r - b * 50;
            if (hi == 0) mybuf[swz(ln, 0)] = (f16)(t * DTCO);   // k0 = t value
            const float* __restrict__ px = x + (size_t)b * 5000 + (size_t)hi * 50 + t;
            const int rb = ln * KA;
#pragma unroll
            for (int i = 0; i < 50; ++i) {
                const int d = 2 * i + hi;          // hi=0: even d, hi=1: odd d
                const float v = px[(size_t)(2 * i) * 50];
                mybuf[rb + ((1 + d) ^ xr)] = (f16)v;
            }
        }
        // stale cols 101..111 hold previous h2 (finite); W1 k-pad is zero -> harmless

        f32x16 acc[4];

        // ---------- layer 1 (in-place: reads x, then overwrites with h1) ----------
#pragma unroll
        for (int nt = 0; nt < 4; ++nt)
#pragma unroll
            for (int q = 0; q < 16; ++q) acc[nt][q] = 0.f;
        run_layer(lds, W1R, 109, mybuf, ln, hi, acc);
        store_h(mybuf, acc, ln, hi);

        // ---------- layer 2 ----------
#pragma unroll
        for (int nt = 0; nt < 4; ++nt)
#pragma unroll
            for (int q = 0; q < 16; ++q) acc[nt][q] = 0.f;
        run_layer(lds, W2R, 109, mybuf, ln, hi, acc);
        store_h(mybuf, acc, ln, hi);

        // ---------- layer 3 ----------
#pragma unroll
        for (int nt = 0; nt < 4; ++nt)
#pragma unroll
            for (int q = 0; q < 16; ++q) acc[nt][q] = 0.f;
        run_layer(lds, W3R, 99, mybuf, ln, hi, acc);

        // ---------- z*(DT*z + dw), reduce over d, accumulate into out ----------
        int offi[4][4];
#pragma unroll
        for (int qq = 0; qq < 4; ++qq) {
            const int r = R0 + 8 * qq + 4 * hi;
            const int b = (int)((unsigned)r / 50u);
            const int t = r - b * 50;
            const int off0 = b * 5000 + t;
#pragma unroll
            for (int i = 0; i < 4; ++i)
                offi[qq][i] = off0 + i + ((t + i >= 50) ? 4950 : 0);  // batch crossing
        }

        float res[16];
#pragma unroll
        for (int s = 0; s < 16; ++s) res[s] = 0.f;
#pragma unroll
        for (int nt = 0; nt < 4; ++nt) {
            const int d = 32 * nt + ln;
            if (d < DIMX) {
                const float* __restrict__ base = dw + (size_t)d * 50;
#pragma unroll
                for (int qq = 0; qq < 4; ++qq)
#pragma unroll
                    for (int i = 0; i < 4; ++i) {
                        const float dv = base[offi[qq][i]];
                        const float z  = (float)acc[nt][qq * 4 + i] * 0.01f;
                        res[qq * 4 + i] += z * (DTCO * z + dv);   // LAM = 1
                    }
            }
        }
        // sum over the 32 columns held across lanes of each hi-half
#pragma unroll
        for (int s = 0; s < 16; ++s) {
            float v = res[s];
            v += __shfl_xor(v, 1);  v += __shfl_xor(v, 2);  v += __shfl_xor(v, 4);
            v += __shfl_xor(v, 8);  v += __shfl_xor(v, 16);
            res[s] = v;
        }
        float val = 0.f;
#pragma unroll
        for (int s = 0; s < 16; ++s) if (ln == s) val = res[s];
        if (ln >= 16) val = 0.f;

        const int rowl = (ln & 3) + 8 * ((ln >> 2) & 3) + 4 * hi;  // row for ln<16
        const int bA = (int)((unsigned)R0 / 50u);
        const int bB = (int)((unsigned)(R0 + 31) / 50u);
        const int bme = (int)((unsigned)(R0 + rowl) / 50u);
        float u0 = (bme == bA) ? val : 0.f;
        float u1 = val - u0;
#pragma unroll
        for (int off = 1; off < 64; off <<= 1) {
            u0 += __shfl_xor(u0, off);
            u1 += __shfl_xor(u1, off);
        }
        if (lane == 0) atomicAdd(&out[bA], u0);
        if (lane == 1 && bB != bA) atomicAdd(&out[bB], u1);
    }
}

extern "C" void kernel_launch(void* const* d_in, const int* in_sizes, int n_in,
                              void* d_out, int out_size, void* d_ws, size_t ws_size,
                              hipStream_t stream) {
    const float* dw = (const float*)d_in[0];
    const float* x  = (const float*)d_in[1];
    const float* W1 = (const float*)d_in[2];
    const float* W2 = (const float*)d_in[3];
    const float* W3 = (const float*)d_in[4];
    const float* y0 = (const float*)d_in[5];
    float* out = (float*)d_out;

    init_out<<<dim3(32), dim3(256), 0, stream>>>(out, y0);
    bsde_kernel<<<dim3(256), dim3(512), 0, stream>>>(dw, x, W1, W2, W3, out);
}

// Round 5
// 431.362 us; speedup vs baseline: 1.6075x; 1.6075x over previous
//
#include <hip/hip_runtime.h>

// Deep-BSDE fused forward, round 3 design (2nd resubmit — broker timeouts, never measured).
// y[b] = y0 + sum_t [ DT*sum_d z^2 + sum_d z*dw ] -- all (b,t) rows independent.
// Design: 1024-thread blocks (16 waves), zero in-loop barriers. Each wave owns a
// 16-row (b,t) tile end-to-end in a private 4KB LDS slice (in-place x->h1->h2),
// full-N per wave via 16x16x32 f16 MFMA (acc = 7 x f32x4 = 28 VGPRs, no spills).
// Weights staged once, transposed+swizzled, in shared LDS (82KB). Total 144KB LDS.

#define DIMX 100
#define TS   50
#define HID  110
#define KA   128            // f16 elems per LDS row (256 B), XOR-swizzled
#define W1R  0
#define W2R  110
#define W3R  220
#define WR   320            // weight rows
#define NTILES 25600        // 409600 rows / 16
#define NWAVES 4096         // 256 blocks * 16 waves
#define DTCO 0.02f

typedef _Float16 f16;
typedef _Float16 f16x2 __attribute__((ext_vector_type(2)));
typedef _Float16 f16x8 __attribute__((ext_vector_type(8)));
typedef float    f32x4 __attribute__((ext_vector_type(4)));

// permute 8-elem (16 B) blocks within a 128-elem row by row&7
__device__ __forceinline__ int swz(int row, int col) {
    return row * KA + (col ^ ((row & 7) << 3));
}

__global__ void init_out(float* __restrict__ out, const float* __restrict__ y0) {
    const int i = blockIdx.x * blockDim.x + threadIdx.x;
    if (i < 8192) out[i] = y0[0];
}

__device__ __forceinline__ void run_layer(const f16* __restrict__ lds, int wrbase,
                                          const f16* __restrict__ slice,
                                          int l15, int kg, f32x4 acc[7])
{
#pragma unroll
    for (int ks = 0; ks < 4; ++ks) {
        const int koff = ks * 32 + kg * 8;
        const f16x8 a = *(const f16x8*)(slice + swz(l15, koff));
#pragma unroll
        for (int nt = 0; nt < 7; ++nt) {
            const f16x8 b = *(const f16x8*)(lds + swz(wrbase + 16 * nt + l15, koff));
            acc[nt] = __builtin_amdgcn_mfma_f32_16x16x32_f16(a, b, acc[nt], 0, 0, 0);
        }
    }
}

__device__ __forceinline__ void store_h(f16* __restrict__ slice, const f32x4 acc[7],
                                        int l15, int kg)
{
#pragma unroll
    for (int nt = 0; nt < 7; ++nt) {
        const int col = 16 * nt + l15;             // 0..111
        const bool live = col < HID;
#pragma unroll
        for (int q = 0; q < 4; ++q) {
            const int row = kg * 4 + q;
            float v = live ? (float)acc[nt][q] : 0.f;
            v = v > 0.f ? v : 0.f;                 // relu (junk cols -> 0)
            slice[swz(row, col)] = (f16)v;
        }
    }
}

__launch_bounds__(1024, 4)
__global__ void bsde_kernel(const float* __restrict__ dw, const float* __restrict__ x,
                            const float* __restrict__ W1, const float* __restrict__ W2,
                            const float* __restrict__ W3, float* __restrict__ out)
{
    __shared__ __align__(16) f16 lds[(WR + 16 * 16) * KA];   // 576 rows * 256 B = 147456 B

    const int tid  = threadIdx.x;
    const int lane = tid & 63;
    const int w    = tid >> 6;      // wave 0..15
    const int l15  = lane & 15;
    const int kg   = lane >> 4;     // k-group / row-quad group 0..3
    f16* __restrict__ slice = lds + (WR + w * 16) * KA;

    // ---------------- prepass: zero LDS, stage weights transposed+swizzled ----------------
    {
        int4* p = (int4*)lds;
        const int n = (int)(sizeof(lds) / sizeof(int4));
        for (int i = tid; i < n; i += 1024) p[i] = int4{0, 0, 0, 0};
    }
    __syncthreads();
    // Layer-1 k-permutation: A cols 0..99 = x[d], col 100 = t-coef.
    // W1 is [101][110] row-major (k,n): Wt1[n][d] = W1[d+1][n]; Wt1[n][100] = W1[0][n].
    for (int e = tid; e < 101 * HID; e += 1024) {
        const int k = e / HID, n = e - k * HID;
        const int col = (k == 0) ? 100 : (k - 1);
        lds[swz(W1R + n, col)] = (f16)W1[e];
    }
    for (int e = tid; e < HID * HID; e += 1024) {
        const int k = e / HID, n = e - k * HID;
        lds[swz(W2R + n, k)] = (f16)W2[e];
    }
    for (int e = tid; e < HID * DIMX; e += 1024) {
        const int k = e / DIMX, n = e - k * DIMX;
        lds[swz(W3R + n, k)] = (f16)W3[e];
    }
    __syncthreads();
    // ---------------- no barriers from here: waves fully independent ----------------

    const int wid = blockIdx.x * 16 + w;

    for (int tile = wid; tile < NTILES; tile += NWAVES) {
        const int R0 = tile * 16;

        // ---- stage x: 16 rows x 100 d, float2 along t packed to b32 along d ----
        // 400 tasks = 50 d-pairs x 8 t-pairs. 50 even => t-pairs never cross b.
        for (int task = lane; task < 400; task += 64) {
            const int tp = task & 7;
            const int dp = task >> 3;
            const int r  = R0 + 2 * tp;
            const int b  = (int)((unsigned)r / 50u);
            const int t  = r - 50 * b;
            const float* px = x + (size_t)b * 5000 + (size_t)(2 * dp) * 50 + t;
            const float2 v0 = *(const float2*)px;          // d=2dp,  t..t+1
            const float2 v1 = *(const float2*)(px + 50);   // d=2dp+1, t..t+1
            const int rl = 2 * tp;
            f16x2 w0; w0[0] = (f16)v0.x; w0[1] = (f16)v1.x;
            f16x2 w1; w1[0] = (f16)v0.y; w1[1] = (f16)v1.y;
            *(f16x2*)(slice + swz(rl,     2 * dp)) = w0;
            *(f16x2*)(slice + swz(rl + 1, 2 * dp)) = w1;
        }
        if (lane < 16) {
            const int r = R0 + lane;
            const int b = (int)((unsigned)r / 50u);
            const int t = r - 50 * b;
            slice[swz(lane, 100)] = (f16)(t * DTCO);       // t-coef at k=100
        }
        // stale cols 101..109 hold previous h2 (finite); W1t k-pad there is 0 -> harmless

        f32x4 acc[7];

        // ---- layer 1 ----
#pragma unroll
        for (int i = 0; i < 7; ++i) { acc[i][0] = 0.f; acc[i][1] = 0.f; acc[i][2] = 0.f; acc[i][3] = 0.f; }
        run_layer(lds, W1R, slice, l15, kg, acc);
        store_h(slice, acc, l15, kg);

        // ---- layer 2 ----
#pragma unroll
        for (int i = 0; i < 7; ++i) { acc[i][0] = 0.f; acc[i][1] = 0.f; acc[i][2] = 0.f; acc[i][3] = 0.f; }
        run_layer(lds, W2R, slice, l15, kg, acc);
        store_h(slice, acc, l15, kg);

        // ---- layer 3 ----
#pragma unroll
        for (int i = 0; i < 7; ++i) { acc[i][0] = 0.f; acc[i][1] = 0.f; acc[i][2] = 0.f; acc[i][3] = 0.f; }
        run_layer(lds, W3R, slice, l15, kg, acc);
        // (W3 n-rows >99 read junk rows; those output cols are masked below via d<100)

        // ---- z*(DT*z + dw), reduce over d, 1-2 atomics per row-quad ----
        // C/D layout: col d = 16nt+l15, rows t = R0 + kg*4 + q (4 consecutive t).
        float res0 = 0.f, res1 = 0.f, res2 = 0.f, res3 = 0.f;
        const int rq = R0 + kg * 4;
        const int b0 = (int)((unsigned)rq / 50u);
        const int t0 = rq - 50 * b0;               // even
        const int cross = (t0 + 2 >= TS) ? 1 : 0;  // quad may cross b between q=1,2
        const int b2 = b0 + cross;
        const int t2 = cross ? (t0 + 2 - TS) : (t0 + 2);
        const size_t base0 = (size_t)b0 * 5000 + (size_t)t0;
        const size_t base2 = (size_t)b2 * 5000 + (size_t)t2;
#pragma unroll
        for (int nt = 0; nt < 7; ++nt) {
            const int d = 16 * nt + l15;
            if (d < DIMX) {
                const float2 u01 = *(const float2*)(dw + base0 + (size_t)d * 50);
                const float2 u23 = *(const float2*)(dw + base2 + (size_t)d * 50);
                float z;
                z = (float)acc[nt][0] * 0.01f; res0 += z * (DTCO * z + u01.x);
                z = (float)acc[nt][1] * 0.01f; res1 += z * (DTCO * z + u01.y);
                z = (float)acc[nt][2] * 0.01f; res2 += z * (DTCO * z + u23.x);
                z = (float)acc[nt][3] * 0.01f; res3 += z * (DTCO * z + u23.y);
            }
        }
#pragma unroll
        for (int off = 1; off < 16; off <<= 1) {
            res0 += __shfl_xor(res0, off);
            res1 += __shfl_xor(res1, off);
            res2 += __shfl_xor(res2, off);
            res3 += __shfl_xor(res3, off);
        }
        if (l15 == 0) {
            const float u0 = res0 + res1;          // rows t0, t0+1 -> b0 always
            const float u1 = res2 + res3;          // rows t2, t2+1 -> b2
            if (cross) {
                atomicAdd(&out[b0], u0);
                atomicAdd(&out[b2], u1);
            } else {
                atomicAdd(&out[b0], u0 + u1);
            }
        }
    }
}

extern "C" void kernel_launch(void* const* d_in, const int* in_sizes, int n_in,
                              void* d_out, int out_size, void* d_ws, size_t ws_size,
                              hipStream_t stream) {
    const float* dw = (const float*)d_in[0];
    const float* x  = (const float*)d_in[1];
    const float* W1 = (const float*)d_in[2];
    const float* W2 = (const float*)d_in[3];
    const float* W3 = (const float*)d_in[4];
    const float* y0 = (const float*)d_in[5];
    float* out = (float*)d_out;

    init_out<<<dim3(32), dim3(256), 0, stream>>>(out, y0);
    bsde_kernel<<<dim3(256), dim3(1024), 0, stream>>>(dw, x, W1, W2, W3, out);
}